// Round 1
// baseline (448.867 us; speedup 1.0000x reference)
//
#include <hip/hip_runtime.h>
#include <float.h>

#define NN 10000
#define EE 320000
#define BB 4
#define DD 128
#define HH 4
#define DHH 32

// ---------------- weight transpose: fc_w [e][d] -> wT [d][e]; mlp_w [o][k] -> mlpT [k][o]
__global__ void transpose_weights(const float* __restrict__ fc0, const float* __restrict__ fc1,
                                  const float* __restrict__ mlp,
                                  float* __restrict__ wT0, float* __restrict__ wT1,
                                  float* __restrict__ mlpT) {
    int idx = blockIdx.x * 256 + threadIdx.x;
    if (idx < 128 * 128) {
        int e = idx >> 7, d = idx & 127;
        wT0[d * 128 + e] = fc0[idx];
        wT1[d * 128 + e] = fc1[idx];
    }
    if (idx < 128 * 256) {
        int o = idx >> 8, k = idx & 255;
        mlpT[k * 128 + o] = mlp[idx];
    }
}

// ---------------- CSR build ----------------
__global__ void count_edges(const int* __restrict__ dst, int* __restrict__ cnt) {
    int e = blockIdx.x * 256 + threadIdx.x;
    if (e < EE) atomicAdd(&cnt[dst[e]], 1);
}

__global__ void scan_kernel(const int* __restrict__ cnt, int* __restrict__ row_off) {
    __shared__ int part[1024];
    int t = threadIdx.x;
    const int CH = 10;  // 1024*10 >= NN
    int loc[CH];
    int s = 0;
#pragma unroll
    for (int j = 0; j < CH; ++j) {
        int i = t * CH + j;
        int v = (i < NN) ? cnt[i] : 0;
        loc[j] = s;
        s += v;
    }
    part[t] = s;
    __syncthreads();
    for (int off = 1; off < 1024; off <<= 1) {
        int v = (t >= off) ? part[t - off] : 0;
        __syncthreads();
        part[t] += v;
        __syncthreads();
    }
    int pre = (t > 0) ? part[t - 1] : 0;
#pragma unroll
    for (int j = 0; j < CH; ++j) {
        int i = t * CH + j;
        if (i < NN) row_off[i] = pre + loc[j];
    }
    if (t == 0) row_off[NN] = part[1023];
}

__global__ void scatter_edges(const int* __restrict__ dst, const int* __restrict__ row_off,
                              int* __restrict__ cursor, int* __restrict__ edge_ids) {
    int e = blockIdx.x * 256 + threadIdx.x;
    if (e < EE) {
        int d = dst[e];
        int p = atomicAdd(&cursor[d], 1);
        edge_ids[row_off[d] + p] = e;
    }
}

// ---------------- GEMM: out[row][o] = sum_k A[row][k] * Wt[k][o]  (O = 128)
// optional fused attention epilogue (el/er) and bias.
template <int K, bool ATTN, bool BIAS>
__global__ __launch_bounds__(256) void gemm_kernel(
    const float* __restrict__ A, int lda,
    const float* __restrict__ Wt,          // [K][128]
    const float* __restrict__ al, const float* __restrict__ ar,
    const float* __restrict__ bias,
    float* __restrict__ out, int ldo,
    float* __restrict__ el_out, float* __restrict__ er_out) {
    __shared__ float A_lds[32 * K];
    int tid = threadIdx.x;
    int row0 = blockIdx.x * 32;

    // stage 32 rows x K of A (float4, coalesced)
#pragma unroll
    for (int it = 0; it < K / 32; ++it) {
        int flat = (it * 256 + tid) * 4;
        int r = flat / K, c = flat % K;
        float4 v = *reinterpret_cast<const float4*>(A + (size_t)(row0 + r) * lda + c);
        *reinterpret_cast<float4*>(&A_lds[r * K + c]) = v;
    }
    __syncthreads();

    int o_lane = tid & 31;
    int rgrp = tid >> 5;  // 8 groups x 4 rows = 32 rows
    float acc[4][4];
#pragma unroll
    for (int i = 0; i < 4; ++i)
#pragma unroll
        for (int j = 0; j < 4; ++j) acc[i][j] = 0.f;

#pragma unroll 4
    for (int k = 0; k < K; ++k) {
        float a0 = A_lds[(rgrp * 4 + 0) * K + k];
        float a1 = A_lds[(rgrp * 4 + 1) * K + k];
        float a2 = A_lds[(rgrp * 4 + 2) * K + k];
        float a3 = A_lds[(rgrp * 4 + 3) * K + k];
        float w0 = Wt[k * 128 + o_lane];
        float w1 = Wt[k * 128 + o_lane + 32];
        float w2 = Wt[k * 128 + o_lane + 64];
        float w3 = Wt[k * 128 + o_lane + 96];
        acc[0][0] += a0 * w0; acc[0][1] += a0 * w1; acc[0][2] += a0 * w2; acc[0][3] += a0 * w3;
        acc[1][0] += a1 * w0; acc[1][1] += a1 * w1; acc[1][2] += a1 * w2; acc[1][3] += a1 * w3;
        acc[2][0] += a2 * w0; acc[2][1] += a2 * w1; acc[2][2] += a2 * w2; acc[2][3] += a2 * w3;
        acc[3][0] += a3 * w0; acc[3][1] += a3 * w1; acc[3][2] += a3 * w2; acc[3][3] += a3 * w3;
    }

#pragma unroll
    for (int ri = 0; ri < 4; ++ri) {
        int row = row0 + rgrp * 4 + ri;
#pragma unroll
        for (int oj = 0; oj < 4; ++oj) {
            int o = o_lane + 32 * oj;
            float v = acc[ri][oj];
            if (BIAS) v += bias[o];
            out[(size_t)row * ldo + o] = v;
        }
    }

    if (ATTN) {
        // head = oj (since O=128 = H*DH, o = oj*32 + o_lane -> h=oj, dh=o_lane)
#pragma unroll
        for (int ri = 0; ri < 4; ++ri) {
#pragma unroll
            for (int oj = 0; oj < 4; ++oj) {
                float pe = acc[ri][oj] * al[oj * 32 + o_lane];
                float pr = acc[ri][oj] * ar[oj * 32 + o_lane];
#pragma unroll
                for (int sh = 16; sh >= 1; sh >>= 1) {
                    pe += __shfl_xor(pe, sh, 32);
                    pr += __shfl_xor(pr, sh, 32);
                }
                if (o_lane == 0) {
                    int row = row0 + rgrp * 4 + ri;
                    el_out[row * 4 + oj] = pe;
                    er_out[row * 4 + oj] = pr;
                }
            }
        }
    }
}

// ---------------- per-dst-node softmax stats: m, den over incoming edges
__global__ __launch_bounds__(256) void stats_kernel(
    const int* __restrict__ row_off, const int* __restrict__ edge_ids,
    const int* __restrict__ src, const float* __restrict__ ew,
    const float* __restrict__ el, const float* __restrict__ er,
    float* __restrict__ m_out, float* __restrict__ den_out) {
    int tid = threadIdx.x;
    int n = blockIdx.x * 4 + (tid >> 6);
    int lane = tid & 63;
    int bh = lane & 15, rep = lane >> 4;
    int b = bh >> 2, h = bh & 3;
    int start = row_off[n], end = row_off[n + 1];
    float er_v = er[((size_t)b * NN + n) * 4 + h];

    float mx = -FLT_MAX;
    for (int i = start + rep; i < end; i += 4) {
        int eid = edge_ids[i];
        int s = src[eid];
        float w = ew[eid];
        float sc = el[((size_t)b * NN + s) * 4 + h] + er_v;
        sc = sc > 0.f ? sc : 0.1f * sc;
        sc *= w;
        mx = fmaxf(mx, sc);
    }
    mx = fmaxf(mx, __shfl_xor(mx, 16, 64));
    mx = fmaxf(mx, __shfl_xor(mx, 32, 64));

    float sm = 0.f;
    for (int i = start + rep; i < end; i += 4) {
        int eid = edge_ids[i];
        int s = src[eid];
        float w = ew[eid];
        float sc = el[((size_t)b * NN + s) * 4 + h] + er_v;
        sc = sc > 0.f ? sc : 0.1f * sc;
        sc *= w;
        sm += __expf(sc - mx);
    }
    sm += __shfl_xor(sm, 16, 64);
    sm += __shfl_xor(sm, 32, 64);

    if (rep == 0) {
        m_out[n * 16 + bh] = (mx == -FLT_MAX) ? 0.f : mx;
        den_out[n * 16 + bh] = sm;
    }
}

// ---------------- per-dst-node aggregation + fused out_fc(relu) -> hcat half
__global__ __launch_bounds__(512) void aggregate_kernel(
    const int* __restrict__ row_off, const int* __restrict__ edge_ids,
    const int* __restrict__ src, const float* __restrict__ ew,
    const float* __restrict__ el, const float* __restrict__ er,
    const float* __restrict__ m_in, const float* __restrict__ den_in,
    const float* __restrict__ feat, const float* __restrict__ out_w,
    const float* __restrict__ out_b, float* __restrict__ hcat, int layer_off) {
    const int CHUNK = 256;
    __shared__ float acc_lds[16][33];
    __shared__ float owt[32][33];
    __shared__ int s_src[CHUNK];
    __shared__ float s_w[CHUNK];

    int tid = threadIdx.x;
    // out_w [o][d] -> owt[d][o] (transposed, padded)
    for (int i = tid; i < 1024; i += 512) {
        int o = i >> 5, d = i & 31;
        owt[d][o] = out_w[i];
    }

    int n = blockIdx.x;
    int bh = tid >> 5, d = tid & 31;
    int b = bh >> 2, h = bh & 3;
    int start = row_off[n], end = row_off[n + 1];
    float er_v = er[((size_t)b * NN + n) * 4 + h];
    float m_v = m_in[n * 16 + bh];
    float den = den_in[n * 16 + bh];
    float inv_den = (den == 0.f) ? 1.f : 1.f / den;

    float acc = 0.f;
    for (int base = start; base < end; base += CHUNK) {
        int cnum = end - base;
        if (cnum > CHUNK) cnum = CHUNK;
        for (int j = tid; j < cnum; j += 512) {
            int eid = edge_ids[base + j];
            s_src[j] = src[eid];
            s_w[j] = ew[eid];
        }
        __syncthreads();
#pragma unroll 4
        for (int j = 0; j < cnum; ++j) {
            int s = s_src[j];
            float w = s_w[j];
            float sc = el[((size_t)b * NN + s) * 4 + h] + er_v;
            sc = sc > 0.f ? sc : 0.1f * sc;
            sc *= w;
            float a = __expf(sc - m_v) * inv_den;
            acc += a * feat[((size_t)b * NN + s) * 128 + h * 32 + d];
        }
        __syncthreads();
    }

    acc_lds[bh][d] = acc;
    __syncthreads();

    // out_fc: thread (bh, o=d): out = relu(sum_dd acc[dd]*out_w[o][dd] + out_b[o])
    float v = out_b[d];
#pragma unroll
    for (int dd = 0; dd < 32; ++dd) v += acc_lds[bh][dd] * owt[dd][d];
    v = fmaxf(v, 0.f);
    hcat[((size_t)b * NN + n) * 256 + layer_off + h * 32 + d] = v;
}

extern "C" void kernel_launch(void* const* d_in, const int* in_sizes, int n_in,
                              void* d_out, int out_size, void* d_ws, size_t ws_size,
                              hipStream_t stream) {
    const float* features = (const float*)d_in[0];
    const int* src = (const int*)d_in[1];
    const int* dst = (const int*)d_in[2];
    const float* edge_w = (const float*)d_in[3];
    const float* fc_w0 = (const float*)d_in[4];
    const float* al0 = (const float*)d_in[5];
    const float* ar0 = (const float*)d_in[6];
    const float* out_w0 = (const float*)d_in[7];
    const float* out_b0 = (const float*)d_in[8];
    const float* fc_w1 = (const float*)d_in[9];
    const float* al1 = (const float*)d_in[10];
    const float* ar1 = (const float*)d_in[11];
    const float* out_w1 = (const float*)d_in[12];
    const float* out_b1 = (const float*)d_in[13];
    const float* mlp_w = (const float*)d_in[14];
    const float* mlp_b = (const float*)d_in[15];
    float* out = (float*)d_out;

    char* p = (char*)d_ws;
    auto take = [&](size_t bytes) {
        char* cur = p;
        p += (bytes + 255) & ~(size_t)255;
        return cur;
    };
    float* wT0 = (float*)take(128 * 128 * 4);
    float* wT1 = (float*)take(128 * 128 * 4);
    float* mlpT = (float*)take(256 * 128 * 4);
    float* feat = (float*)take((size_t)BB * NN * 128 * 4);
    float* hcat = (float*)take((size_t)BB * NN * 256 * 4);
    float* el = (float*)take((size_t)BB * NN * HH * 4);
    float* er = (float*)take((size_t)BB * NN * HH * 4);
    float* mbuf = (float*)take((size_t)NN * 16 * 4);
    float* den = (float*)take((size_t)NN * 16 * 4);
    int* cnt = (int*)take((size_t)NN * 4);
    int* cursor = (int*)take((size_t)NN * 4);
    int* row_off = (int*)take((size_t)(NN + 1) * 4);
    int* edge_ids = (int*)take((size_t)EE * 4);
    (void)ws_size; (void)in_sizes; (void)n_in; (void)out_size;

    // weight prep + CSR build
    transpose_weights<<<128, 256, 0, stream>>>(fc_w0, fc_w1, mlp_w, wT0, wT1, mlpT);
    hipMemsetAsync(cnt, 0, (size_t)NN * 4, stream);
    hipMemsetAsync(cursor, 0, (size_t)NN * 4, stream);
    count_edges<<<EE / 256, 256, 0, stream>>>(dst, cnt);
    scan_kernel<<<1, 1024, 0, stream>>>(cnt, row_off);
    scatter_edges<<<EE / 256, 256, 0, stream>>>(dst, row_off, cursor, edge_ids);

    const int GEMM_GRID = (BB * NN) / 32;  // 1250

    // ---- layer 0 ----
    gemm_kernel<128, true, false><<<GEMM_GRID, 256, 0, stream>>>(
        features, 128, wT0, al0, ar0, nullptr, feat, 128, el, er);
    stats_kernel<<<NN / 4, 256, 0, stream>>>(row_off, edge_ids, src, edge_w, el, er, mbuf, den);
    aggregate_kernel<<<NN, 512, 0, stream>>>(row_off, edge_ids, src, edge_w, el, er, mbuf, den,
                                             feat, out_w0, out_b0, hcat, 0);
    // ---- layer 1 ---- (input = hcat[:, 0:128], output -> hcat[:, 128:256])
    gemm_kernel<128, true, false><<<GEMM_GRID, 256, 0, stream>>>(
        hcat, 256, wT1, al1, ar1, nullptr, feat, 128, el, er);
    stats_kernel<<<NN / 4, 256, 0, stream>>>(row_off, edge_ids, src, edge_w, el, er, mbuf, den);
    aggregate_kernel<<<NN, 512, 0, stream>>>(row_off, edge_ids, src, edge_w, el, er, mbuf, den,
                                             feat, out_w1, out_b1, hcat, 128);
    // ---- MLP head ----
    gemm_kernel<256, false, true><<<GEMM_GRID, 256, 0, stream>>>(
        hcat, 256, mlpT, nullptr, nullptr, mlp_b, out, 128, nullptr, nullptr);
}

// Round 2
// 379.352 us; speedup vs baseline: 1.1832x; 1.1832x over previous
//
#include <hip/hip_runtime.h>
#include <float.h>

#define NN 10000
#define EE 320000
#define BB 4
#define DD 128
#define HH 4
#define DHH 32
#define CHUNK 128

// ---------------- weight transpose: fc_w [e][d] -> wT [d][e]; mlp_w [o][k] -> mlpT [k][o]
__global__ void transpose_weights(const float* __restrict__ fc0, const float* __restrict__ fc1,
                                  const float* __restrict__ mlp,
                                  float* __restrict__ wT0, float* __restrict__ wT1,
                                  float* __restrict__ mlpT) {
    int idx = blockIdx.x * 256 + threadIdx.x;
    if (idx < 128 * 128) {
        int e = idx >> 7, d = idx & 127;
        wT0[d * 128 + e] = fc0[idx];
        wT1[d * 128 + e] = fc1[idx];
    }
    if (idx < 128 * 256) {
        int o = idx >> 8, k = idx & 255;
        mlpT[k * 128 + o] = mlp[idx];
    }
}

// ---------------- CSR build ----------------
__global__ void count_edges(const int* __restrict__ dst, int* __restrict__ cnt) {
    int e = blockIdx.x * 256 + threadIdx.x;
    if (e < EE) atomicAdd(&cnt[dst[e]], 1);
}

__global__ void scan_kernel(const int* __restrict__ cnt, int* __restrict__ row_off) {
    __shared__ int part[1024];
    int t = threadIdx.x;
    const int CH = 10;  // 1024*10 >= NN
    int loc[CH];
    int s = 0;
#pragma unroll
    for (int j = 0; j < CH; ++j) {
        int i = t * CH + j;
        int v = (i < NN) ? cnt[i] : 0;
        loc[j] = s;
        s += v;
    }
    part[t] = s;
    __syncthreads();
    for (int off = 1; off < 1024; off <<= 1) {
        int v = (t >= off) ? part[t - off] : 0;
        __syncthreads();
        part[t] += v;
        __syncthreads();
    }
    int pre = (t > 0) ? part[t - 1] : 0;
#pragma unroll
    for (int j = 0; j < CH; ++j) {
        int i = t * CH + j;
        if (i < NN) row_off[i] = pre + loc[j];
    }
    if (t == 0) row_off[NN] = part[1023];
}

__global__ void scatter_edges(const int* __restrict__ dst, const int* __restrict__ row_off,
                              int* __restrict__ cursor, int* __restrict__ edge_ids) {
    int e = blockIdx.x * 256 + threadIdx.x;
    if (e < EE) {
        int d = dst[e];
        int p = atomicAdd(&cursor[d], 1);
        edge_ids[row_off[d] + p] = e;
    }
}

// ---------------- GEMM: out[row][o] = sum_k A[row][k] * Wt[k][o]  (O = 128)
// 64-row tile, A and W both staged in LDS per 32-k tile; 8x4 accs/thread.
template <int K, bool ATTN, bool BIAS>
__global__ __launch_bounds__(256) void gemm_kernel(
    const float* __restrict__ A, int lda,
    const float* __restrict__ Wt,          // [K][128]
    const float* __restrict__ al, const float* __restrict__ ar,
    const float* __restrict__ bias,
    float* __restrict__ out, int ldo,
    float* __restrict__ el_out, float* __restrict__ er_out) {
    __shared__ float A_s[64][33];
    __shared__ float W_s[32][128];
    int tid = threadIdx.x;
    int row0 = blockIdx.x * 64;
    int o_lane = tid & 31;
    int rgrp = tid >> 5;  // 8 groups x 8 rows

    float acc[8][4];
#pragma unroll
    for (int i = 0; i < 8; ++i)
#pragma unroll
        for (int j = 0; j < 4; ++j) acc[i][j] = 0.f;

    for (int kt = 0; kt < K; kt += 32) {
        // stage A tile: 64 rows x 32 cols
#pragma unroll
        for (int it = 0; it < 2; ++it) {
            int idx = it * 256 + tid;           // 0..511
            int r = idx >> 3, c = (idx & 7) * 4;
            float4 v = *reinterpret_cast<const float4*>(A + (size_t)(row0 + r) * lda + kt + c);
            A_s[r][c + 0] = v.x; A_s[r][c + 1] = v.y; A_s[r][c + 2] = v.z; A_s[r][c + 3] = v.w;
        }
        // stage W tile: 32 k x 128 o
#pragma unroll
        for (int it = 0; it < 4; ++it) {
            int idx = it * 256 + tid;           // 0..1023
            int k = idx >> 5, o = (idx & 31) * 4;
            *reinterpret_cast<float4*>(&W_s[k][o]) =
                *reinterpret_cast<const float4*>(Wt + (size_t)(kt + k) * 128 + o);
        }
        __syncthreads();
#pragma unroll 8
        for (int k = 0; k < 32; ++k) {
            float w0 = W_s[k][o_lane];
            float w1 = W_s[k][o_lane + 32];
            float w2 = W_s[k][o_lane + 64];
            float w3 = W_s[k][o_lane + 96];
#pragma unroll
            for (int ri = 0; ri < 8; ++ri) {
                float a = A_s[rgrp * 8 + ri][k];
                acc[ri][0] += a * w0; acc[ri][1] += a * w1;
                acc[ri][2] += a * w2; acc[ri][3] += a * w3;
            }
        }
        __syncthreads();
    }

#pragma unroll
    for (int ri = 0; ri < 8; ++ri) {
        int row = row0 + rgrp * 8 + ri;
#pragma unroll
        for (int oj = 0; oj < 4; ++oj) {
            float v = acc[ri][oj];
            if (BIAS) v += bias[o_lane + 32 * oj];
            out[(size_t)row * ldo + o_lane + 32 * oj] = v;
        }
    }

    if (ATTN) {
        // o = oj*32 + o_lane -> head h = oj, dh = o_lane
#pragma unroll
        for (int ri = 0; ri < 8; ++ri) {
#pragma unroll
            for (int oj = 0; oj < 4; ++oj) {
                float pe = acc[ri][oj] * al[oj * 32 + o_lane];
                float pr = acc[ri][oj] * ar[oj * 32 + o_lane];
#pragma unroll
                for (int sh = 16; sh >= 1; sh >>= 1) {
                    pe += __shfl_xor(pe, sh, 32);
                    pr += __shfl_xor(pr, sh, 32);
                }
                if (o_lane == 0) {
                    int row = row0 + rgrp * 8 + ri;
                    el_out[row * 4 + oj] = pe;
                    er_out[row * 4 + oj] = pr;
                }
            }
        }
    }
}

// ---------------- fused per-dst-node: online softmax + aggregation + out_fc(relu)
// 128 threads/block, one block per dst node.
// phase-1 role: bh1 = tid&15, js = tid>>4 (8 j-slots)  -- computes attention weights
// phase-2 role: bh2 = tid>>3, dq = tid&7 (float4 over d) -- gathers feat
__global__ __launch_bounds__(128) void gat_aggregate(
    const int* __restrict__ row_off, const int* __restrict__ edge_ids,
    const int* __restrict__ src, const float* __restrict__ ew,
    const float* __restrict__ el, const float* __restrict__ er,
    const float* __restrict__ feat, const float* __restrict__ out_w,
    const float* __restrict__ out_b, float* __restrict__ hcat, int layer_off) {
    __shared__ int s_src[CHUNK];
    __shared__ float s_w[CHUNK];
    __shared__ float s_red[8][16];
    __shared__ float s_m[16];
    __shared__ float s_scale[16];
    __shared__ float s_den[16];
    __shared__ float s_union[16 * 132];  // s_p[16][132] during loop; owt_t[32][33]+accl[16][33] after

    int tid = threadIdx.x;
    int n = blockIdx.x;
    int start = row_off[n], end = row_off[n + 1];

    int bh1 = tid & 15, js = tid >> 4;
    int b1 = bh1 >> 2, h1 = bh1 & 3;
    float er1 = er[((size_t)b1 * NN + n) * 4 + h1];

    int bh2 = tid >> 3, dq = tid & 7;
    int b2 = bh2 >> 2, h2 = bh2 & 3;
    const float* fbase = feat + (size_t)b2 * NN * 128 + h2 * 32 + dq * 4;

    if (tid < 16) { s_m[tid] = -FLT_MAX; s_den[tid] = 0.f; }
    float4 acc = make_float4(0.f, 0.f, 0.f, 0.f);

    for (int base = start; base < end; base += CHUNK) {
        int cnum = end - base;
        if (cnum > CHUNK) cnum = CHUNK;
        // stage edge data
        for (int j = tid; j < cnum; j += 128) {
            int eid = edge_ids[base + j];
            s_src[j] = src[eid];
            s_w[j] = ew[eid];
        }
        __syncthreads();
        // raw scores + local max
        float lmax = -FLT_MAX;
        for (int j = js; j < cnum; j += 8) {
            int s = s_src[j];
            float sc = el[((size_t)b1 * NN + s) * 4 + h1] + er1;
            sc = sc > 0.f ? sc : 0.1f * sc;
            sc *= s_w[j];
            s_union[bh1 * 132 + j] = sc;
            lmax = fmaxf(lmax, sc);
        }
        s_red[js][bh1] = lmax;
        __syncthreads();
        if (tid < 16) {
            float m_c = s_red[0][tid];
#pragma unroll
            for (int k = 1; k < 8; ++k) m_c = fmaxf(m_c, s_red[k][tid]);
            float m_old = s_m[tid];
            float m_new = fmaxf(m_old, m_c);
            s_scale[tid] = __expf(m_old - m_new);
            s_m[tid] = m_new;
        }
        __syncthreads();
        // exponentiate + local den
        float lden = 0.f;
        float m_b = s_m[bh1];
        for (int j = js; j < cnum; j += 8) {
            float p = __expf(s_union[bh1 * 132 + j] - m_b);
            s_union[bh1 * 132 + j] = p;
            lden += p;
        }
        s_red[js][bh1] = lden;
        __syncthreads();
        if (tid < 16) {
            float d_c = 0.f;
#pragma unroll
            for (int k = 0; k < 8; ++k) d_c += s_red[k][tid];
            s_den[tid] = s_den[tid] * s_scale[tid] + d_c;
        }
        // gather + accumulate (rescale by online-softmax factor)
        float sc2 = s_scale[bh2];
        acc.x *= sc2; acc.y *= sc2; acc.z *= sc2; acc.w *= sc2;
        const float* prow = s_union + bh2 * 132;
        for (int j = 0; j < cnum; ++j) {
            float p = prow[j];
            int s = s_src[j];
            float4 f = *reinterpret_cast<const float4*>(fbase + (size_t)s * 128);
            acc.x += p * f.x; acc.y += p * f.y; acc.z += p * f.z; acc.w += p * f.w;
        }
        __syncthreads();
    }
    __syncthreads();  // s_den final; s_union free for reuse

    // stage out_w transposed: owt_t[d][o] at s_union[d*33+o]  (indices 0..1054)
    for (int i = tid; i < 1024; i += 128) {
        int o = i >> 5, d = i & 31;
        s_union[d * 33 + o] = out_w[i];
    }
    // normalized acc -> accl[bh][d] at s_union[1056 + bh*33 + d]
    float den_v = s_den[bh2];
    float inv_den = (den_v == 0.f) ? 1.f : 1.f / den_v;
    float* accl = s_union + 1056;
    accl[bh2 * 33 + dq * 4 + 0] = acc.x * inv_den;
    accl[bh2 * 33 + dq * 4 + 1] = acc.y * inv_den;
    accl[bh2 * 33 + dq * 4 + 2] = acc.z * inv_den;
    accl[bh2 * 33 + dq * 4 + 3] = acc.w * inv_den;
    __syncthreads();

    // out_fc: thread (bh2, dq) computes outputs o = dq*4..dq*4+3
    float o0 = out_b[dq * 4 + 0], o1 = out_b[dq * 4 + 1];
    float o2 = out_b[dq * 4 + 2], o3 = out_b[dq * 4 + 3];
    const float* accr = accl + bh2 * 33;
#pragma unroll 8
    for (int dd = 0; dd < 32; ++dd) {
        float a = accr[dd];
        const float* wr = s_union + dd * 33 + dq * 4;
        o0 += a * wr[0]; o1 += a * wr[1]; o2 += a * wr[2]; o3 += a * wr[3];
    }
    float4 ov;
    ov.x = fmaxf(o0, 0.f); ov.y = fmaxf(o1, 0.f);
    ov.z = fmaxf(o2, 0.f); ov.w = fmaxf(o3, 0.f);
    *reinterpret_cast<float4*>(hcat + ((size_t)b2 * NN + n) * 256 + layer_off + h2 * 32 + dq * 4) = ov;
}

extern "C" void kernel_launch(void* const* d_in, const int* in_sizes, int n_in,
                              void* d_out, int out_size, void* d_ws, size_t ws_size,
                              hipStream_t stream) {
    const float* features = (const float*)d_in[0];
    const int* src = (const int*)d_in[1];
    const int* dst = (const int*)d_in[2];
    const float* edge_w = (const float*)d_in[3];
    const float* fc_w0 = (const float*)d_in[4];
    const float* al0 = (const float*)d_in[5];
    const float* ar0 = (const float*)d_in[6];
    const float* out_w0 = (const float*)d_in[7];
    const float* out_b0 = (const float*)d_in[8];
    const float* fc_w1 = (const float*)d_in[9];
    const float* al1 = (const float*)d_in[10];
    const float* ar1 = (const float*)d_in[11];
    const float* out_w1 = (const float*)d_in[12];
    const float* out_b1 = (const float*)d_in[13];
    const float* mlp_w = (const float*)d_in[14];
    const float* mlp_b = (const float*)d_in[15];
    float* out = (float*)d_out;

    char* p = (char*)d_ws;
    auto take = [&](size_t bytes) {
        char* cur = p;
        p += (bytes + 255) & ~(size_t)255;
        return cur;
    };
    float* wT0 = (float*)take(128 * 128 * 4);
    float* wT1 = (float*)take(128 * 128 * 4);
    float* mlpT = (float*)take(256 * 128 * 4);
    float* feat = (float*)take((size_t)BB * NN * 128 * 4);
    float* hcat = (float*)take((size_t)BB * NN * 256 * 4);
    float* el = (float*)take((size_t)BB * NN * HH * 4);
    float* er = (float*)take((size_t)BB * NN * HH * 4);
    int* cnt = (int*)take((size_t)NN * 4);
    int* cursor = (int*)take((size_t)NN * 4);
    int* row_off = (int*)take((size_t)(NN + 1) * 4);
    int* edge_ids = (int*)take((size_t)EE * 4);
    (void)ws_size; (void)in_sizes; (void)n_in; (void)out_size;

    // weight prep + CSR build
    transpose_weights<<<128, 256, 0, stream>>>(fc_w0, fc_w1, mlp_w, wT0, wT1, mlpT);
    hipMemsetAsync(cnt, 0, (size_t)NN * 4, stream);
    hipMemsetAsync(cursor, 0, (size_t)NN * 4, stream);
    count_edges<<<EE / 256, 256, 0, stream>>>(dst, cnt);
    scan_kernel<<<1, 1024, 0, stream>>>(cnt, row_off);
    scatter_edges<<<EE / 256, 256, 0, stream>>>(dst, row_off, cursor, edge_ids);

    const int GEMM_GRID = (BB * NN) / 64;  // 625

    // ---- layer 0 ----
    gemm_kernel<128, true, false><<<GEMM_GRID, 256, 0, stream>>>(
        features, 128, wT0, al0, ar0, nullptr, feat, 128, el, er);
    gat_aggregate<<<NN, 128, 0, stream>>>(row_off, edge_ids, src, edge_w, el, er,
                                          feat, out_w0, out_b0, hcat, 0);
    // ---- layer 1 ---- (input = hcat[:, 0:128], output -> hcat[:, 128:256])
    gemm_kernel<128, true, false><<<GEMM_GRID, 256, 0, stream>>>(
        hcat, 256, wT1, al1, ar1, nullptr, feat, 128, el, er);
    gat_aggregate<<<NN, 128, 0, stream>>>(row_off, edge_ids, src, edge_w, el, er,
                                          feat, out_w1, out_b1, hcat, 128);
    // ---- MLP head ----
    gemm_kernel<256, false, true><<<GEMM_GRID, 256, 0, stream>>>(
        hcat, 256, mlpT, nullptr, nullptr, mlp_b, out, 128, nullptr, nullptr);
}

// Round 4
// 282.670 us; speedup vs baseline: 1.5880x; 1.3420x over previous
//
#include <hip/hip_runtime.h>
#include <hip/hip_fp16.h>
#include <float.h>

#define NN 10000
#define EE 320000
#define BB 4
#define DD 128
#define HH 4
#define DHH 32
#define CHUNK 128

union H4 { uint2 u2; __half2 h2[2]; };

// ---------------- weight transpose: fc_w [e][d] -> wT [d][e]; mlp_w [o][k] -> mlpT [k][o]
__global__ void transpose_weights(const float* __restrict__ fc0, const float* __restrict__ fc1,
                                  const float* __restrict__ mlp,
                                  float* __restrict__ wT0, float* __restrict__ wT1,
                                  float* __restrict__ mlpT) {
    int idx = blockIdx.x * 256 + threadIdx.x;
    if (idx < 128 * 128) {
        int e = idx >> 7, d = idx & 127;
        wT0[d * 128 + e] = fc0[idx];
        wT1[d * 128 + e] = fc1[idx];
    }
    if (idx < 128 * 256) {
        int o = idx >> 8, k = idx & 255;
        mlpT[k * 128 + o] = mlp[idx];
    }
}

// ---------------- CSR build ----------------
__global__ void count_edges(const int* __restrict__ dst, int* __restrict__ cnt) {
    int e = blockIdx.x * 256 + threadIdx.x;
    if (e < EE) atomicAdd(&cnt[dst[e]], 1);
}

__global__ void scan_kernel(const int* __restrict__ cnt, int* __restrict__ row_off) {
    __shared__ int part[1024];
    int t = threadIdx.x;
    const int CH = 10;  // 1024*10 >= NN
    int loc[CH];
    int s = 0;
#pragma unroll
    for (int j = 0; j < CH; ++j) {
        int i = t * CH + j;
        int v = (i < NN) ? cnt[i] : 0;
        loc[j] = s;
        s += v;
    }
    part[t] = s;
    __syncthreads();
    for (int off = 1; off < 1024; off <<= 1) {
        int v = (t >= off) ? part[t - off] : 0;
        __syncthreads();
        part[t] += v;
        __syncthreads();
    }
    int pre = (t > 0) ? part[t - 1] : 0;
#pragma unroll
    for (int j = 0; j < CH; ++j) {
        int i = t * CH + j;
        if (i < NN) row_off[i] = pre + loc[j];
    }
    if (t == 0) row_off[NN] = part[1023];
}

__global__ void scatter_edges(const int* __restrict__ dst, const int* __restrict__ row_off,
                              int* __restrict__ cursor, int* __restrict__ edge_ids) {
    int e = blockIdx.x * 256 + threadIdx.x;
    if (e < EE) {
        int d = dst[e];
        int p = atomicAdd(&cursor[d], 1);
        edge_ids[row_off[d] + p] = e;
    }
}

// ---------------- GEMM: out[row][o] = sum_k A[row][k] * Wt[k][o]  (O = 128)
// 64-row tile, A and W staged in LDS per 32-k tile; 8x4 accs/thread.
template <int K, bool HALF_OUT, bool BIAS>
__global__ __launch_bounds__(256) void gemm_kernel(
    const float* __restrict__ A, int lda,
    const float* __restrict__ Wt,          // [K][128]
    const float* __restrict__ bias,
    float* __restrict__ outf, __half* __restrict__ outh, int ldo) {
    __shared__ float A_s[64][33];
    __shared__ float W_s[32][128];
    int tid = threadIdx.x;
    int row0 = blockIdx.x * 64;
    int o_lane = tid & 31;
    int rgrp = tid >> 5;  // 8 groups x 8 rows

    float acc[8][4];
#pragma unroll
    for (int i = 0; i < 8; ++i)
#pragma unroll
        for (int j = 0; j < 4; ++j) acc[i][j] = 0.f;

    for (int kt = 0; kt < K; kt += 32) {
#pragma unroll
        for (int it = 0; it < 2; ++it) {
            int idx = it * 256 + tid;           // 0..511
            int r = idx >> 3, c = (idx & 7) * 4;
            float4 v = *reinterpret_cast<const float4*>(A + (size_t)(row0 + r) * lda + kt + c);
            A_s[r][c + 0] = v.x; A_s[r][c + 1] = v.y; A_s[r][c + 2] = v.z; A_s[r][c + 3] = v.w;
        }
#pragma unroll
        for (int it = 0; it < 4; ++it) {
            int idx = it * 256 + tid;           // 0..1023
            int k = idx >> 5, o = (idx & 31) * 4;
            *reinterpret_cast<float4*>(&W_s[k][o]) =
                *reinterpret_cast<const float4*>(Wt + (size_t)(kt + k) * 128 + o);
        }
        __syncthreads();
#pragma unroll 8
        for (int k = 0; k < 32; ++k) {
            float w0 = W_s[k][o_lane];
            float w1 = W_s[k][o_lane + 32];
            float w2 = W_s[k][o_lane + 64];
            float w3 = W_s[k][o_lane + 96];
#pragma unroll
            for (int ri = 0; ri < 8; ++ri) {
                float a = A_s[rgrp * 8 + ri][k];
                acc[ri][0] += a * w0; acc[ri][1] += a * w1;
                acc[ri][2] += a * w2; acc[ri][3] += a * w3;
            }
        }
        __syncthreads();
    }

#pragma unroll
    for (int ri = 0; ri < 8; ++ri) {
        int row = row0 + rgrp * 8 + ri;
#pragma unroll
        for (int oj = 0; oj < 4; ++oj) {
            int o = o_lane + 32 * oj;
            float v = acc[ri][oj];
            if (BIAS) v += bias[o];
            if (HALF_OUT) outh[(size_t)row * ldo + o] = __float2half(v);
            else outf[(size_t)row * ldo + o] = v;
        }
    }
}

// ---------------- el/er from fp16 feat: el[b,n,h] = sum_d feat[b,n,h,d]*al[h,d]
__global__ __launch_bounds__(256) void elr_kernel(
    const __half* __restrict__ feat_h, const float* __restrict__ al,
    const float* __restrict__ ar, float* __restrict__ el, float* __restrict__ er) {
    __shared__ float s_al[128], s_ar[128];
    int tid = threadIdx.x;
    if (tid < 128) s_al[tid] = al[tid];
    else s_ar[tid - 128] = ar[tid - 128];
    __syncthreads();
    int idx = blockIdx.x * 256 + tid;  // (b*NN+n)*4 + h
    if (idx < BB * NN * HH) {
        int h = idx & 3;
        const __half* row = feat_h + (size_t)(idx >> 2) * 128 + h * 32;
        float al_acc = 0.f, ar_acc = 0.f;
#pragma unroll
        for (int q = 0; q < 8; ++q) {
            H4 u;
            u.u2 = *reinterpret_cast<const uint2*>(row + q * 4);
            float2 f0 = __half22float2(u.h2[0]);
            float2 f1 = __half22float2(u.h2[1]);
            int d = h * 32 + q * 4;
            al_acc += f0.x * s_al[d] + f0.y * s_al[d + 1] + f1.x * s_al[d + 2] + f1.y * s_al[d + 3];
            ar_acc += f0.x * s_ar[d] + f0.y * s_ar[d + 1] + f1.x * s_ar[d + 2] + f1.y * s_ar[d + 3];
        }
        el[idx] = al_acc;
        er[idx] = ar_acc;
    }
}

// ---------------- fused per-dst-node: online softmax + aggregation + out_fc(relu)
// 128 threads/block, one block per dst node. (R2-proven structure; fp16 feat loads only.)
// phase-1 role: bh1 = tid&15, js = tid>>4 (8 j-slots)  -- computes attention weights
// phase-2 role: bh2 = tid>>3, dq = tid&7 (4 halves over d) -- gathers feat
__global__ __launch_bounds__(128) void gat_aggregate(
    const int* __restrict__ row_off, const int* __restrict__ edge_ids,
    const int* __restrict__ src, const float* __restrict__ ew,
    const float* __restrict__ el, const float* __restrict__ er,
    const __half* __restrict__ feat_h, const float* __restrict__ out_w,
    const float* __restrict__ out_b, float* __restrict__ hcat, int layer_off) {
    __shared__ int s_src[CHUNK];
    __shared__ float s_w[CHUNK];
    __shared__ float s_red[8][16];
    __shared__ float s_m[16];
    __shared__ float s_scale[16];
    __shared__ float s_den[16];
    __shared__ float s_union[16 * 132];  // s_p[16][132] during loop; owt[32][33]+accl[16][33] after

    int tid = threadIdx.x;
    int n = blockIdx.x;
    int start = row_off[n], end = row_off[n + 1];

    int bh1 = tid & 15, js = tid >> 4;
    int b1 = bh1 >> 2, h1 = bh1 & 3;
    float er1 = er[((size_t)b1 * NN + n) * 4 + h1];

    int bh2 = tid >> 3, dq = tid & 7;
    int b2 = bh2 >> 2, h2 = bh2 & 3;
    const __half* fbase = feat_h + (size_t)b2 * NN * 128 + h2 * 32 + dq * 4;

    if (tid < 16) { s_m[tid] = -FLT_MAX; s_den[tid] = 0.f; }
    float4 acc = make_float4(0.f, 0.f, 0.f, 0.f);
    __syncthreads();

    for (int base = start; base < end; base += CHUNK) {
        int cnum = end - base;
        if (cnum > CHUNK) cnum = CHUNK;
        // stage edge data
        for (int j = tid; j < cnum; j += 128) {
            int eid = edge_ids[base + j];
            s_src[j] = src[eid];
            s_w[j] = ew[eid];
        }
        __syncthreads();
        // raw scores + local max
        float lmax = -FLT_MAX;
        for (int j = js; j < cnum; j += 8) {
            int s = s_src[j];
            float sc = el[((size_t)b1 * NN + s) * 4 + h1] + er1;
            sc = sc > 0.f ? sc : 0.1f * sc;
            sc *= s_w[j];
            s_union[bh1 * 132 + j] = sc;
            lmax = fmaxf(lmax, sc);
        }
        s_red[js][bh1] = lmax;
        __syncthreads();
        if (tid < 16) {
            float m_c = s_red[0][tid];
#pragma unroll
            for (int k = 1; k < 8; ++k) m_c = fmaxf(m_c, s_red[k][tid]);
            float m_old = s_m[tid];
            float m_new = fmaxf(m_old, m_c);
            s_scale[tid] = __expf(m_old - m_new);
            s_m[tid] = m_new;
        }
        __syncthreads();
        // exponentiate + local den
        float lden = 0.f;
        float m_b = s_m[bh1];
        for (int j = js; j < cnum; j += 8) {
            float p = __expf(s_union[bh1 * 132 + j] - m_b);
            s_union[bh1 * 132 + j] = p;
            lden += p;
        }
        s_red[js][bh1] = lden;
        __syncthreads();
        if (tid < 16) {
            float d_c = 0.f;
#pragma unroll
            for (int k = 0; k < 8; ++k) d_c += s_red[k][tid];
            s_den[tid] = s_den[tid] * s_scale[tid] + d_c;
        }
        // gather + accumulate (rescale by online-softmax factor)
        float sc2 = s_scale[bh2];
        acc.x *= sc2; acc.y *= sc2; acc.z *= sc2; acc.w *= sc2;
        const float* prow = s_union + bh2 * 132;
        for (int j = 0; j < cnum; ++j) {
            float p = prow[j];
            int s = s_src[j];
            H4 u;
            u.u2 = *reinterpret_cast<const uint2*>(fbase + (size_t)s * 128);
            float2 f0 = __half22float2(u.h2[0]);
            float2 f1 = __half22float2(u.h2[1]);
            acc.x += p * f0.x; acc.y += p * f0.y;
            acc.z += p * f1.x; acc.w += p * f1.y;
        }
        __syncthreads();
    }
    __syncthreads();  // s_den final; s_union free for reuse

    // stage out_w transposed: owt[d][o] at s_union[d*33+o]  (indices 0..1054)
    for (int i = tid; i < 1024; i += 128) {
        int o = i >> 5, d = i & 31;
        s_union[d * 33 + o] = out_w[i];
    }
    // normalized acc -> accl[bh][d] at s_union[1056 + bh*33 + d]
    float den_v = s_den[bh2];
    float inv_den = (den_v == 0.f) ? 1.f : 1.f / den_v;
    float* accl = s_union + 1056;
    accl[bh2 * 33 + dq * 4 + 0] = acc.x * inv_den;
    accl[bh2 * 33 + dq * 4 + 1] = acc.y * inv_den;
    accl[bh2 * 33 + dq * 4 + 2] = acc.z * inv_den;
    accl[bh2 * 33 + dq * 4 + 3] = acc.w * inv_den;
    __syncthreads();

    // out_fc: thread (bh2, dq) computes outputs o = dq*4..dq*4+3
    float o0 = out_b[dq * 4 + 0], o1 = out_b[dq * 4 + 1];
    float o2 = out_b[dq * 4 + 2], o3 = out_b[dq * 4 + 3];
    const float* accr = accl + bh2 * 33;
#pragma unroll 8
    for (int dd = 0; dd < 32; ++dd) {
        float a = accr[dd];
        const float* wr = s_union + dd * 33 + dq * 4;
        o0 += a * wr[0]; o1 += a * wr[1]; o2 += a * wr[2]; o3 += a * wr[3];
    }
    float4 ov;
    ov.x = fmaxf(o0, 0.f); ov.y = fmaxf(o1, 0.f);
    ov.z = fmaxf(o2, 0.f); ov.w = fmaxf(o3, 0.f);
    *reinterpret_cast<float4*>(hcat + ((size_t)b2 * NN + n) * 256 + layer_off + h2 * 32 + dq * 4) = ov;
}

extern "C" void kernel_launch(void* const* d_in, const int* in_sizes, int n_in,
                              void* d_out, int out_size, void* d_ws, size_t ws_size,
                              hipStream_t stream) {
    const float* features = (const float*)d_in[0];
    const int* src = (const int*)d_in[1];
    const int* dst = (const int*)d_in[2];
    const float* edge_w = (const float*)d_in[3];
    const float* fc_w0 = (const float*)d_in[4];
    const float* al0 = (const float*)d_in[5];
    const float* ar0 = (const float*)d_in[6];
    const float* out_w0 = (const float*)d_in[7];
    const float* out_b0 = (const float*)d_in[8];
    const float* fc_w1 = (const float*)d_in[9];
    const float* al1 = (const float*)d_in[10];
    const float* ar1 = (const float*)d_in[11];
    const float* out_w1 = (const float*)d_in[12];
    const float* out_b1 = (const float*)d_in[13];
    const float* mlp_w = (const float*)d_in[14];
    const float* mlp_b = (const float*)d_in[15];
    float* out = (float*)d_out;

    char* p = (char*)d_ws;
    auto take = [&](size_t bytes) {
        char* cur = p;
        p += (bytes + 255) & ~(size_t)255;
        return cur;
    };
    float* wT0 = (float*)take(128 * 128 * 4);
    float* wT1 = (float*)take(128 * 128 * 4);
    float* mlpT = (float*)take(256 * 128 * 4);
    __half* feat_h = (__half*)take((size_t)BB * NN * 128 * 2);
    float* hcat = (float*)take((size_t)BB * NN * 256 * 4);
    float* el = (float*)take((size_t)BB * NN * HH * 4);
    float* er = (float*)take((size_t)BB * NN * HH * 4);
    int* cnt = (int*)take((size_t)NN * 4);
    int* cursor = (int*)take((size_t)NN * 4);
    int* row_off = (int*)take((size_t)(NN + 1) * 4);
    int* edge_ids = (int*)take((size_t)EE * 4);
    (void)ws_size; (void)in_sizes; (void)n_in; (void)out_size;

    // weight prep + CSR build
    transpose_weights<<<128, 256, 0, stream>>>(fc_w0, fc_w1, mlp_w, wT0, wT1, mlpT);
    hipMemsetAsync(cnt, 0, (size_t)NN * 4, stream);
    hipMemsetAsync(cursor, 0, (size_t)NN * 4, stream);
    count_edges<<<EE / 256, 256, 0, stream>>>(dst, cnt);
    scan_kernel<<<1, 1024, 0, stream>>>(cnt, row_off);
    scatter_edges<<<EE / 256, 256, 0, stream>>>(dst, row_off, cursor, edge_ids);

    const int GEMM_GRID = (BB * NN) / 64;  // 625
    const int ELR_GRID = (BB * NN * HH + 255) / 256;  // 625

    // ---- layer 0 ----
    gemm_kernel<128, true, false><<<GEMM_GRID, 256, 0, stream>>>(
        features, 128, wT0, nullptr, nullptr, feat_h, 128);
    elr_kernel<<<ELR_GRID, 256, 0, stream>>>(feat_h, al0, ar0, el, er);
    gat_aggregate<<<NN, 128, 0, stream>>>(row_off, edge_ids, src, edge_w, el, er,
                                          feat_h, out_w0, out_b0, hcat, 0);
    // ---- layer 1 ---- (input = hcat[:, 0:128], output -> hcat[:, 128:256])
    gemm_kernel<128, true, false><<<GEMM_GRID, 256, 0, stream>>>(
        hcat, 256, wT1, nullptr, nullptr, feat_h, 128);
    elr_kernel<<<ELR_GRID, 256, 0, stream>>>(feat_h, al1, ar1, el, er);
    gat_aggregate<<<NN, 128, 0, stream>>>(row_off, edge_ids, src, edge_w, el, er,
                                          feat_h, out_w1, out_b1, hcat, 128);
    // ---- MLP head ----
    gemm_kernel<256, false, true><<<GEMM_GRID, 256, 0, stream>>>(
        hcat, 256, mlpT, mlp_b, out, nullptr, 128);
}

// Round 5
// 213.086 us; speedup vs baseline: 2.1065x; 1.3266x over previous
//
#include <hip/hip_runtime.h>
#include <hip/hip_fp16.h>
#include <float.h>

#define NN 10000
#define EE 320000
#define BB 4
#define DD 128
#define HH 4
#define DHH 32
#define CHUNK 128

union H4 { uint2 u2; __half2 h2[2]; };

typedef _Float16 f16x8 __attribute__((ext_vector_type(8)));
typedef float f32x4 __attribute__((ext_vector_type(4)));

// ---------------- pack weights into per-lane MFMA B-fragments (fp16) ----------------
// Bp frag s: i = s&7, lane l = (s>>3)&63, ct = (s>>9)&7, kt = s>>12
// value = W[k][o], k = kt*32 + 8*(l>>4) + i, o = ct*16 + (l&15)
// fc_w is [o][k] (128x128); mlp_w is [o][k] (128x256)
__global__ void pack_weights(const float* __restrict__ fc0, const float* __restrict__ fc1,
                             const float* __restrict__ mlp,
                             __half* __restrict__ bp0, __half* __restrict__ bp1,
                             __half* __restrict__ bpm) {
    int s = blockIdx.x * 256 + threadIdx.x;  // 0..32767
    int i = s & 7, l = (s >> 3) & 63, ct = (s >> 9) & 7, kt = s >> 12;
    int k = kt * 32 + 8 * (l >> 4) + i;
    int o = ct * 16 + (l & 15);
    bpm[s] = __float2half(mlp[o * 256 + k]);
    if (s < 16384) {
        bp0[s] = __float2half(fc0[o * 128 + k]);
        bp1[s] = __float2half(fc1[o * 128 + k]);
    }
}

// ---------------- CSR build ----------------
__global__ void count_edges(const int* __restrict__ dst, int* __restrict__ cnt) {
    int e = blockIdx.x * 256 + threadIdx.x;
    if (e < EE) atomicAdd(&cnt[dst[e]], 1);
}

__global__ void scan_kernel(const int* __restrict__ cnt, int* __restrict__ row_off) {
    __shared__ int part[1024];
    int t = threadIdx.x;
    const int CH = 10;  // 1024*10 >= NN
    int loc[CH];
    int s = 0;
#pragma unroll
    for (int j = 0; j < CH; ++j) {
        int i = t * CH + j;
        int v = (i < NN) ? cnt[i] : 0;
        loc[j] = s;
        s += v;
    }
    part[t] = s;
    __syncthreads();
    for (int off = 1; off < 1024; off <<= 1) {
        int v = (t >= off) ? part[t - off] : 0;
        __syncthreads();
        part[t] += v;
        __syncthreads();
    }
    int pre = (t > 0) ? part[t - 1] : 0;
#pragma unroll
    for (int j = 0; j < CH; ++j) {
        int i = t * CH + j;
        if (i < NN) row_off[i] = pre + loc[j];
    }
    if (t == 0) row_off[NN] = part[1023];
}

__global__ void scatter_edges(const int* __restrict__ dst, const int* __restrict__ row_off,
                              int* __restrict__ cursor, int* __restrict__ edge_ids) {
    int e = blockIdx.x * 256 + threadIdx.x;
    if (e < EE) {
        int d = dst[e];
        int p = atomicAdd(&cursor[d], 1);
        edge_ids[row_off[d] + p] = e;
    }
}

// ---------------- MFMA GEMM: out[row][o] = sum_k A[row][k] * W[k][o], O=128 ----------------
// 64 rows/block, 256 threads = 4 waves; wave w owns rows [w*16, w*16+16).
// A staged in LDS fp16 with XOR swizzle (byte ^= (row&7)<<4); B pre-packed per-lane frags.
// A-frag slot (g=l>>4, i): k = kt*32 + 8g + i  -- same map as pack_weights, so the
// contraction is correct for any HW k-permutation (A and B permute identically).
template <int K, bool A_HALF, bool HALF_OUT, bool BIAS>
__global__ __launch_bounds__(256) void mfma_gemm(
    const void* __restrict__ A_, int lda,
    const __half* __restrict__ Bp,
    const float* __restrict__ bias,
    __half* __restrict__ outh, float* __restrict__ outf, int ldo) {
    __shared__ __half A_s[64 * K];
    int tid = threadIdx.x;
    int row0 = blockIdx.x * 64;

    if (A_HALF) {
        const __half* A = (const __half*)A_;
#pragma unroll
        for (int it = 0; it < (64 * K / 8) / 256; ++it) {
            int s = it * 256 + tid;
            int r = s / (K / 8), c8 = s % (K / 8);
            uint4 v = *reinterpret_cast<const uint4*>(A + (size_t)(row0 + r) * lda + c8 * 8);
            int byte = (r * K + c8 * 8) * 2;
            byte ^= (r & 7) << 4;
            *reinterpret_cast<uint4*>((char*)A_s + byte) = v;
        }
    } else {
        const float* A = (const float*)A_;
#pragma unroll
        for (int it = 0; it < (64 * K / 4) / 256; ++it) {
            int s = it * 256 + tid;
            int r = s / (K / 4), c4 = s % (K / 4);
            float4 v = *reinterpret_cast<const float4*>(A + (size_t)(row0 + r) * lda + c4 * 4);
            __half h[4];
            h[0] = __float2half(v.x); h[1] = __float2half(v.y);
            h[2] = __float2half(v.z); h[3] = __float2half(v.w);
            int byte = (r * K + c4 * 4) * 2;
            byte ^= (r & 7) << 4;
            *reinterpret_cast<uint2*>((char*)A_s + byte) = *reinterpret_cast<uint2*>(h);
        }
    }
    __syncthreads();

    int l = tid & 63, w = tid >> 6;
    int g = l >> 4, r15 = l & 15;
    f32x4 acc[8] = {};

#pragma unroll
    for (int kt = 0; kt < K / 32; ++kt) {
        int row = w * 16 + r15;
        int byte = (row * K + kt * 32 + 8 * g) * 2;
        byte ^= (row & 7) << 4;
        f16x8 a = *reinterpret_cast<const f16x8*>((const char*)A_s + byte);
        const f16x8* bp = reinterpret_cast<const f16x8*>(Bp) + (size_t)(kt * 8) * 64 + l;
#pragma unroll
        for (int ct = 0; ct < 8; ++ct) {
            f16x8 b = bp[(size_t)ct * 64];
            acc[ct] = __builtin_amdgcn_mfma_f32_16x16x32_f16(a, b, acc[ct], 0, 0, 0);
        }
    }

#pragma unroll
    for (int ct = 0; ct < 8; ++ct) {
        int col = ct * 16 + r15;
#pragma unroll
        for (int reg = 0; reg < 4; ++reg) {
            int row = row0 + w * 16 + g * 4 + reg;
            float v = acc[ct][reg];
            if (BIAS) v += bias[col];
            if (HALF_OUT) outh[(size_t)row * ldo + col] = __float2half(v);
            else outf[(size_t)row * ldo + col] = v;
        }
    }
}

// ---------------- el/er from fp16 feat: el[b,n,h] = sum_d feat[b,n,h,d]*al[h,d]
__global__ __launch_bounds__(256) void elr_kernel(
    const __half* __restrict__ feat_h, const float* __restrict__ al,
    const float* __restrict__ ar, float* __restrict__ el, float* __restrict__ er) {
    __shared__ float s_al[128], s_ar[128];
    int tid = threadIdx.x;
    if (tid < 128) s_al[tid] = al[tid];
    else s_ar[tid - 128] = ar[tid - 128];
    __syncthreads();
    int idx = blockIdx.x * 256 + tid;  // (b*NN+n)*4 + h
    if (idx < BB * NN * HH) {
        int h = idx & 3;
        const __half* row = feat_h + (size_t)(idx >> 2) * 128 + h * 32;
        float al_acc = 0.f, ar_acc = 0.f;
#pragma unroll
        for (int q = 0; q < 8; ++q) {
            H4 u;
            u.u2 = *reinterpret_cast<const uint2*>(row + q * 4);
            float2 f0 = __half22float2(u.h2[0]);
            float2 f1 = __half22float2(u.h2[1]);
            int d = h * 32 + q * 4;
            al_acc += f0.x * s_al[d] + f0.y * s_al[d + 1] + f1.x * s_al[d + 2] + f1.y * s_al[d + 3];
            ar_acc += f0.x * s_ar[d] + f0.y * s_ar[d + 1] + f1.x * s_ar[d + 2] + f1.y * s_ar[d + 3];
        }
        el[idx] = al_acc;
        er[idx] = ar_acc;
    }
}

// ---------------- fused per-dst-node: online softmax + aggregation + out_fc(relu)
// 128 threads/block, one block per dst node. (R2/R4-proven structure; fp16 hcat store.)
__global__ __launch_bounds__(128) void gat_aggregate(
    const int* __restrict__ row_off, const int* __restrict__ edge_ids,
    const int* __restrict__ src, const float* __restrict__ ew,
    const float* __restrict__ el, const float* __restrict__ er,
    const __half* __restrict__ feat_h, const float* __restrict__ out_w,
    const float* __restrict__ out_b, __half* __restrict__ hcat, int layer_off) {
    __shared__ int s_src[CHUNK];
    __shared__ float s_w[CHUNK];
    __shared__ float s_red[8][16];
    __shared__ float s_m[16];
    __shared__ float s_scale[16];
    __shared__ float s_den[16];
    __shared__ float s_union[16 * 132];  // s_p[16][132] during loop; owt[32][33]+accl[16][33] after

    int tid = threadIdx.x;
    int n = blockIdx.x;
    int start = row_off[n], end = row_off[n + 1];

    int bh1 = tid & 15, js = tid >> 4;
    int b1 = bh1 >> 2, h1 = bh1 & 3;
    float er1 = er[((size_t)b1 * NN + n) * 4 + h1];

    int bh2 = tid >> 3, dq = tid & 7;
    int b2 = bh2 >> 2, h2 = bh2 & 3;
    const __half* fbase = feat_h + (size_t)b2 * NN * 128 + h2 * 32 + dq * 4;

    if (tid < 16) { s_m[tid] = -FLT_MAX; s_den[tid] = 0.f; }
    float4 acc = make_float4(0.f, 0.f, 0.f, 0.f);
    __syncthreads();

    for (int base = start; base < end; base += CHUNK) {
        int cnum = end - base;
        if (cnum > CHUNK) cnum = CHUNK;
        // stage edge data
        for (int j = tid; j < cnum; j += 128) {
            int eid = edge_ids[base + j];
            s_src[j] = src[eid];
            s_w[j] = ew[eid];
        }
        __syncthreads();
        // raw scores + local max
        float lmax = -FLT_MAX;
        for (int j = js; j < cnum; j += 8) {
            int s = s_src[j];
            float sc = el[((size_t)b1 * NN + s) * 4 + h1] + er1;
            sc = sc > 0.f ? sc : 0.1f * sc;
            sc *= s_w[j];
            s_union[bh1 * 132 + j] = sc;
            lmax = fmaxf(lmax, sc);
        }
        s_red[js][bh1] = lmax;
        __syncthreads();
        if (tid < 16) {
            float m_c = s_red[0][tid];
#pragma unroll
            for (int k = 1; k < 8; ++k) m_c = fmaxf(m_c, s_red[k][tid]);
            float m_old = s_m[tid];
            float m_new = fmaxf(m_old, m_c);
            s_scale[tid] = __expf(m_old - m_new);
            s_m[tid] = m_new;
        }
        __syncthreads();
        // exponentiate + local den
        float lden = 0.f;
        float m_b = s_m[bh1];
        for (int j = js; j < cnum; j += 8) {
            float p = __expf(s_union[bh1 * 132 + j] - m_b);
            s_union[bh1 * 132 + j] = p;
            lden += p;
        }
        s_red[js][bh1] = lden;
        __syncthreads();
        if (tid < 16) {
            float d_c = 0.f;
#pragma unroll
            for (int k = 0; k < 8; ++k) d_c += s_red[k][tid];
            s_den[tid] = s_den[tid] * s_scale[tid] + d_c;
        }
        // gather + accumulate (rescale by online-softmax factor)
        float sc2 = s_scale[bh2];
        acc.x *= sc2; acc.y *= sc2; acc.z *= sc2; acc.w *= sc2;
        const float* prow = s_union + bh2 * 132;
#pragma unroll 4
        for (int j = 0; j < cnum; ++j) {
            float p = prow[j];
            int s = s_src[j];
            H4 u;
            u.u2 = *reinterpret_cast<const uint2*>(fbase + (size_t)s * 128);
            float2 f0 = __half22float2(u.h2[0]);
            float2 f1 = __half22float2(u.h2[1]);
            acc.x += p * f0.x; acc.y += p * f0.y;
            acc.z += p * f1.x; acc.w += p * f1.y;
        }
        __syncthreads();
    }
    __syncthreads();  // s_den final; s_union free for reuse

    // stage out_w transposed: owt[d][o] at s_union[d*33+o]
    for (int i = tid; i < 1024; i += 128) {
        int o = i >> 5, d = i & 31;
        s_union[d * 33 + o] = out_w[i];
    }
    // normalized acc -> accl[bh][d] at s_union[1056 + bh*33 + d]
    float den_v = s_den[bh2];
    float inv_den = (den_v == 0.f) ? 1.f : 1.f / den_v;
    float* accl = s_union + 1056;
    accl[bh2 * 33 + dq * 4 + 0] = acc.x * inv_den;
    accl[bh2 * 33 + dq * 4 + 1] = acc.y * inv_den;
    accl[bh2 * 33 + dq * 4 + 2] = acc.z * inv_den;
    accl[bh2 * 33 + dq * 4 + 3] = acc.w * inv_den;
    __syncthreads();

    // out_fc: thread (bh2, dq) computes outputs o = dq*4..dq*4+3
    float o0 = out_b[dq * 4 + 0], o1 = out_b[dq * 4 + 1];
    float o2 = out_b[dq * 4 + 2], o3 = out_b[dq * 4 + 3];
    const float* accr = accl + bh2 * 33;
#pragma unroll 8
    for (int dd = 0; dd < 32; ++dd) {
        float a = accr[dd];
        const float* wr = s_union + dd * 33 + dq * 4;
        o0 += a * wr[0]; o1 += a * wr[1]; o2 += a * wr[2]; o3 += a * wr[3];
    }
    H4 ov;
    ov.h2[0] = __floats2half2_rn(fmaxf(o0, 0.f), fmaxf(o1, 0.f));
    ov.h2[1] = __floats2half2_rn(fmaxf(o2, 0.f), fmaxf(o3, 0.f));
    *reinterpret_cast<uint2*>(hcat + ((size_t)b2 * NN + n) * 256 + layer_off + h2 * 32 + dq * 4) = ov.u2;
}

extern "C" void kernel_launch(void* const* d_in, const int* in_sizes, int n_in,
                              void* d_out, int out_size, void* d_ws, size_t ws_size,
                              hipStream_t stream) {
    const float* features = (const float*)d_in[0];
    const int* src = (const int*)d_in[1];
    const int* dst = (const int*)d_in[2];
    const float* edge_w = (const float*)d_in[3];
    const float* fc_w0 = (const float*)d_in[4];
    const float* al0 = (const float*)d_in[5];
    const float* ar0 = (const float*)d_in[6];
    const float* out_w0 = (const float*)d_in[7];
    const float* out_b0 = (const float*)d_in[8];
    const float* fc_w1 = (const float*)d_in[9];
    const float* al1 = (const float*)d_in[10];
    const float* ar1 = (const float*)d_in[11];
    const float* out_w1 = (const float*)d_in[12];
    const float* out_b1 = (const float*)d_in[13];
    const float* mlp_w = (const float*)d_in[14];
    const float* mlp_b = (const float*)d_in[15];
    float* out = (float*)d_out;

    char* p = (char*)d_ws;
    auto take = [&](size_t bytes) {
        char* cur = p;
        p += (bytes + 255) & ~(size_t)255;
        return cur;
    };
    __half* bp0 = (__half*)take(16384 * 2);
    __half* bp1 = (__half*)take(16384 * 2);
    __half* bpm = (__half*)take(32768 * 2);
    __half* feat_h = (__half*)take((size_t)BB * NN * 128 * 2);
    __half* hcat = (__half*)take((size_t)BB * NN * 256 * 2);
    float* el = (float*)take((size_t)BB * NN * HH * 4);
    float* er = (float*)take((size_t)BB * NN * HH * 4);
    int* cnt = (int*)take((size_t)NN * 4);
    int* cursor = (int*)take((size_t)NN * 4);
    int* row_off = (int*)take((size_t)(NN + 1) * 4);
    int* edge_ids = (int*)take((size_t)EE * 4);
    (void)ws_size; (void)in_sizes; (void)n_in; (void)out_size;

    // weight prep + CSR build
    pack_weights<<<128, 256, 0, stream>>>(fc_w0, fc_w1, mlp_w, bp0, bp1, bpm);
    hipMemsetAsync(cnt, 0, (size_t)NN * 4, stream);
    hipMemsetAsync(cursor, 0, (size_t)NN * 4, stream);
    count_edges<<<EE / 256, 256, 0, stream>>>(dst, cnt);
    scan_kernel<<<1, 1024, 0, stream>>>(cnt, row_off);
    scatter_edges<<<EE / 256, 256, 0, stream>>>(dst, row_off, cursor, edge_ids);

    const int GEMM_GRID = (BB * NN) / 64;  // 625
    const int ELR_GRID = (BB * NN * HH + 255) / 256;  // 625

    // ---- layer 0 ----
    mfma_gemm<128, false, true, false><<<GEMM_GRID, 256, 0, stream>>>(
        features, 128, bp0, nullptr, feat_h, nullptr, 128);
    elr_kernel<<<ELR_GRID, 256, 0, stream>>>(feat_h, al0, ar0, el, er);
    gat_aggregate<<<NN, 128, 0, stream>>>(row_off, edge_ids, src, edge_w, el, er,
                                          feat_h, out_w0, out_b0, hcat, 0);
    // ---- layer 1 ---- (input = hcat[:, 0:128] fp16, output -> hcat[:, 128:256])
    mfma_gemm<128, true, true, false><<<GEMM_GRID, 256, 0, stream>>>(
        hcat, 256, bp1, nullptr, feat_h, nullptr, 128);
    elr_kernel<<<ELR_GRID, 256, 0, stream>>>(feat_h, al1, ar1, el, er);
    gat_aggregate<<<NN, 128, 0, stream>>>(row_off, edge_ids, src, edge_w, el, er,
                                          feat_h, out_w1, out_b1, hcat, 128);
    // ---- MLP head ---- (A = hcat fp16, K=256, fp32 out + bias)
    mfma_gemm<256, true, false, true><<<GEMM_GRID, 256, 0, stream>>>(
        hcat, 256, bpm, mlp_b, nullptr, out, 128);
}

// Round 6
// 211.178 us; speedup vs baseline: 2.1255x; 1.0090x over previous
//
#include <hip/hip_runtime.h>
#include <hip/hip_fp16.h>
#include <float.h>

#define NN 10000
#define EE 320000
#define BB 4
#define DD 128
#define HH 4
#define DHH 32

union H4 { uint2 u2; __half2 h2[2]; };
union H8 { float4 f4; __half2 h2[4]; };

typedef _Float16 f16x8 __attribute__((ext_vector_type(8)));
typedef float f32x4 __attribute__((ext_vector_type(4)));

// ---------------- pack weights into per-lane MFMA B-fragments (fp16) + zero CSR counters
// Bp frag s: i = s&7, lane l = (s>>3)&63, ct = (s>>9)&7, kt = s>>12
// value = W[k][o], k = kt*32 + 8*(l>>4) + i, o = ct*16 + (l&15)
__global__ void pack_weights(const float* __restrict__ fc0, const float* __restrict__ fc1,
                             const float* __restrict__ mlp,
                             __half* __restrict__ bp0, __half* __restrict__ bp1,
                             __half* __restrict__ bpm,
                             int* __restrict__ cnt, int* __restrict__ cursor) {
    int s = blockIdx.x * 256 + threadIdx.x;  // 0..32767
    int i = s & 7, l = (s >> 3) & 63, ct = (s >> 9) & 7, kt = s >> 12;
    int k = kt * 32 + 8 * (l >> 4) + i;
    int o = ct * 16 + (l & 15);
    bpm[s] = __float2half(mlp[o * 256 + k]);
    if (s < 16384) {
        bp0[s] = __float2half(fc0[o * 128 + k]);
        bp1[s] = __float2half(fc1[o * 128 + k]);
    }
    if (s < NN) { cnt[s] = 0; cursor[s] = 0; }
}

// ---------------- CSR build ----------------
__global__ void count_edges(const int* __restrict__ dst, int* __restrict__ cnt) {
    int e = blockIdx.x * 256 + threadIdx.x;
    if (e < EE) atomicAdd(&cnt[dst[e]], 1);
}

__global__ void scan_kernel(const int* __restrict__ cnt, int* __restrict__ row_off) {
    __shared__ int part[1024];
    int t = threadIdx.x;
    const int CH = 10;  // 1024*10 >= NN
    int loc[CH];
    int s = 0;
#pragma unroll
    for (int j = 0; j < CH; ++j) {
        int i = t * CH + j;
        int v = (i < NN) ? cnt[i] : 0;
        loc[j] = s;
        s += v;
    }
    part[t] = s;
    __syncthreads();
    for (int off = 1; off < 1024; off <<= 1) {
        int v = (t >= off) ? part[t - off] : 0;
        __syncthreads();
        part[t] += v;
        __syncthreads();
    }
    int pre = (t > 0) ? part[t - 1] : 0;
#pragma unroll
    for (int j = 0; j < CH; ++j) {
        int i = t * CH + j;
        if (i < NN) row_off[i] = pre + loc[j];
    }
    if (t == 0) row_off[NN] = part[1023];
}

__global__ void scatter_edges(const int* __restrict__ dst, const int* __restrict__ row_off,
                              int* __restrict__ cursor, int* __restrict__ edge_ids) {
    int e = blockIdx.x * 256 + threadIdx.x;
    if (e < EE) {
        int d = dst[e];
        int p = atomicAdd(&cursor[d], 1);
        edge_ids[row_off[d] + p] = e;
    }
}

// ---------------- MFMA GEMM: out[row][o] = sum_k A[row][k] * W[k][o], O=128 ----------------
// (unchanged from R5 — proven)
template <int K, bool A_HALF, bool HALF_OUT, bool BIAS>
__global__ __launch_bounds__(256) void mfma_gemm(
    const void* __restrict__ A_, int lda,
    const __half* __restrict__ Bp,
    const float* __restrict__ bias,
    __half* __restrict__ outh, float* __restrict__ outf, int ldo) {
    __shared__ __half A_s[64 * K];
    int tid = threadIdx.x;
    int row0 = blockIdx.x * 64;

    if (A_HALF) {
        const __half* A = (const __half*)A_;
#pragma unroll
        for (int it = 0; it < (64 * K / 8) / 256; ++it) {
            int s = it * 256 + tid;
            int r = s / (K / 8), c8 = s % (K / 8);
            uint4 v = *reinterpret_cast<const uint4*>(A + (size_t)(row0 + r) * lda + c8 * 8);
            int byte = (r * K + c8 * 8) * 2;
            byte ^= (r & 7) << 4;
            *reinterpret_cast<uint4*>((char*)A_s + byte) = v;
        }
    } else {
        const float* A = (const float*)A_;
#pragma unroll
        for (int it = 0; it < (64 * K / 4) / 256; ++it) {
            int s = it * 256 + tid;
            int r = s / (K / 4), c4 = s % (K / 4);
            float4 v = *reinterpret_cast<const float4*>(A + (size_t)(row0 + r) * lda + c4 * 4);
            __half h[4];
            h[0] = __float2half(v.x); h[1] = __float2half(v.y);
            h[2] = __float2half(v.z); h[3] = __float2half(v.w);
            int byte = (r * K + c4 * 4) * 2;
            byte ^= (r & 7) << 4;
            *reinterpret_cast<uint2*>((char*)A_s + byte) = *reinterpret_cast<uint2*>(h);
        }
    }
    __syncthreads();

    int l = tid & 63, w = tid >> 6;
    int g = l >> 4, r15 = l & 15;
    f32x4 acc[8] = {};

#pragma unroll
    for (int kt = 0; kt < K / 32; ++kt) {
        int row = w * 16 + r15;
        int byte = (row * K + kt * 32 + 8 * g) * 2;
        byte ^= (row & 7) << 4;
        f16x8 a = *reinterpret_cast<const f16x8*>((const char*)A_s + byte);
        const f16x8* bp = reinterpret_cast<const f16x8*>(Bp) + (size_t)(kt * 8) * 64 + l;
#pragma unroll
        for (int ct = 0; ct < 8; ++ct) {
            f16x8 b = bp[(size_t)ct * 64];
            acc[ct] = __builtin_amdgcn_mfma_f32_16x16x32_f16(a, b, acc[ct], 0, 0, 0);
        }
    }

#pragma unroll
    for (int ct = 0; ct < 8; ++ct) {
        int col = ct * 16 + r15;
#pragma unroll
        for (int reg = 0; reg < 4; ++reg) {
            int row = row0 + w * 16 + g * 4 + reg;
            float v = acc[ct][reg];
            if (BIAS) v += bias[col];
            if (HALF_OUT) outh[(size_t)row * ldo + col] = __float2half(v);
            else outf[(size_t)row * ldo + col] = v;
        }
    }
}

// ---------------- el/er from fp16 feat ----------------
__global__ __launch_bounds__(256) void elr_kernel(
    const __half* __restrict__ feat_h, const float* __restrict__ al,
    const float* __restrict__ ar, float* __restrict__ el, float* __restrict__ er) {
    __shared__ float s_al[128], s_ar[128];
    int tid = threadIdx.x;
    if (tid < 128) s_al[tid] = al[tid];
    else s_ar[tid - 128] = ar[tid - 128];
    __syncthreads();
    int idx = blockIdx.x * 256 + tid;  // (b*NN+n)*4 + h
    if (idx < BB * NN * HH) {
        int h = idx & 3;
        const __half* row = feat_h + (size_t)(idx >> 2) * 128 + h * 32;
        float al_acc = 0.f, ar_acc = 0.f;
#pragma unroll
        for (int q = 0; q < 8; ++q) {
            H4 u;
            u.u2 = *reinterpret_cast<const uint2*>(row + q * 4);
            float2 f0 = __half22float2(u.h2[0]);
            float2 f1 = __half22float2(u.h2[1]);
            int d = h * 32 + q * 4;
            al_acc += f0.x * s_al[d] + f0.y * s_al[d + 1] + f1.x * s_al[d + 2] + f1.y * s_al[d + 3];
            ar_acc += f0.x * s_ar[d] + f0.y * s_ar[d + 1] + f1.x * s_ar[d + 2] + f1.y * s_ar[d + 3];
        }
        el[idx] = al_acc;
        er[idx] = ar_acc;
    }
}

// ---------------- wave-per-node fused aggregate: online softmax + gather + out_fc(relu)
// 256 threads = 4 waves; wave wv handles node n = blockIdx.x*4 + wv.
// NO barriers in the main loop (all LDS traffic is wave-private; out_w staged once).
// phase 1: lane = (bh = lane&15, js = lane>>4 in 0..3) computes scores/exp
// phase 2: lane = (bh, dq = lane>>4)  gathers 16 B (8 halves) per edge
#define PSTR 66  // s_p row stride (floats): (66*bh + j) % 32 spreads banks, <=2-way
__global__ __launch_bounds__(256) void gat_aggregate(
    const int* __restrict__ row_off, const int* __restrict__ edge_ids,
    const int* __restrict__ src, const float* __restrict__ ew,
    const float* __restrict__ el, const float* __restrict__ er,
    const __half* __restrict__ feat_h, const float* __restrict__ out_w,
    const float* __restrict__ out_b, __half* __restrict__ hcat, int layer_off) {
    __shared__ float s_owt[32 * 33];      // out_w transposed [d][o]
    __shared__ int s_srcA[4][64];
    __shared__ float s_wA[4][64];
    __shared__ float s_pA[4][16 * PSTR];

    int tid = threadIdx.x;
    for (int i = tid; i < 1024; i += 256) {
        int o = i >> 5, d = i & 31;
        s_owt[d * 33 + o] = out_w[i];
    }
    __syncthreads();  // the only block-wide barrier; s_owt read-only afterwards

    int wv = tid >> 6, lane = tid & 63;
    int n = blockIdx.x * 4 + wv;
    int start = row_off[n], end = row_off[n + 1];
    int* s_src = s_srcA[wv];
    float* s_w = s_wA[wv];
    float* s_p = s_pA[wv];

    int bh = lane & 15, sl = lane >> 4;  // sl = js (phase1) = dq (phase2)
    int b = bh >> 2, h = bh & 3;
    float er1 = er[((size_t)b * NN + n) * 4 + h];
    const __half* fbase = feat_h + (size_t)b * NN * 128 + h * 32 + sl * 8;

    float m_reg = -FLT_MAX, den_reg = 0.f;
    float acc8[8];
#pragma unroll
    for (int i = 0; i < 8; ++i) acc8[i] = 0.f;

    for (int base = start; base < end; base += 64) {
        int cnum = end - base;
        if (cnum > 64) cnum = 64;
        // stage edge data (wave-private LDS; ordered by lgkmcnt)
        if (lane < cnum) {
            int eid = edge_ids[base + lane];
            s_src[lane] = src[eid];
            s_w[lane] = ew[eid];
        }
        // phase 1: raw scores + local max
        float lmax = -FLT_MAX;
#pragma unroll 4
        for (int j = sl; j < cnum; j += 4) {
            int s = s_src[j];
            float sc = el[((size_t)b * NN + s) * 4 + h] + er1;
            sc = sc > 0.f ? sc : 0.1f * sc;
            sc *= s_w[j];
            s_p[bh * PSTR + j] = sc;
            lmax = fmaxf(lmax, sc);
        }
        lmax = fmaxf(lmax, __shfl_xor(lmax, 16, 64));
        lmax = fmaxf(lmax, __shfl_xor(lmax, 32, 64));
        float m_new = fmaxf(m_reg, lmax);
        float scale = __expf(m_reg - m_new);   // exp(-inf)=0 on first chunk
        m_reg = m_new;
        // phase 1b: exponentiate + local den
        float lden = 0.f;
#pragma unroll 4
        for (int j = sl; j < cnum; j += 4) {
            float p = __expf(s_p[bh * PSTR + j] - m_new);
            s_p[bh * PSTR + j] = p;
            lden += p;
        }
        lden += __shfl_xor(lden, 16, 64);
        lden += __shfl_xor(lden, 32, 64);
        den_reg = den_reg * scale + lden;
        // phase 2: gather + accumulate
#pragma unroll
        for (int i = 0; i < 8; ++i) acc8[i] *= scale;
#pragma unroll 8
        for (int j = 0; j < cnum; ++j) {
            float p = s_p[bh * PSTR + j];
            int s = s_src[j];
            H8 u;
            u.f4 = *reinterpret_cast<const float4*>(fbase + (size_t)s * 128);
            float2 f0 = __half22float2(u.h2[0]);
            float2 f1 = __half22float2(u.h2[1]);
            float2 f2 = __half22float2(u.h2[2]);
            float2 f3 = __half22float2(u.h2[3]);
            acc8[0] += p * f0.x; acc8[1] += p * f0.y;
            acc8[2] += p * f1.x; acc8[3] += p * f1.y;
            acc8[4] += p * f2.x; acc8[5] += p * f2.y;
            acc8[6] += p * f3.x; acc8[7] += p * f3.y;
        }
    }

    // epilogue: normalize, stage agg into s_p (dead), out_fc + relu -> hcat fp16
    float inv_den = (den_reg == 0.f) ? 1.f : 1.f / den_reg;
#pragma unroll
    for (int i = 0; i < 8; ++i) s_p[bh * PSTR + sl * 8 + i] = acc8[i] * inv_den;

    float o_acc[8];
#pragma unroll
    for (int i = 0; i < 8; ++i) o_acc[i] = out_b[sl * 8 + i];
#pragma unroll 8
    for (int dd = 0; dd < 32; ++dd) {
        float a = s_p[bh * PSTR + dd];
        const float* wr = s_owt + dd * 33 + sl * 8;
#pragma unroll
        for (int i = 0; i < 8; ++i) o_acc[i] += a * wr[i];
    }
    H8 ov;
#pragma unroll
    for (int k = 0; k < 4; ++k)
        ov.h2[k] = __floats2half2_rn(fmaxf(o_acc[2 * k], 0.f), fmaxf(o_acc[2 * k + 1], 0.f));
    *reinterpret_cast<float4*>(hcat + ((size_t)b * NN + n) * 256 + layer_off + h * 32 + sl * 8) = ov.f4;
}

extern "C" void kernel_launch(void* const* d_in, const int* in_sizes, int n_in,
                              void* d_out, int out_size, void* d_ws, size_t ws_size,
                              hipStream_t stream) {
    const float* features = (const float*)d_in[0];
    const int* src = (const int*)d_in[1];
    const int* dst = (const int*)d_in[2];
    const float* edge_w = (const float*)d_in[3];
    const float* fc_w0 = (const float*)d_in[4];
    const float* al0 = (const float*)d_in[5];
    const float* ar0 = (const float*)d_in[6];
    const float* out_w0 = (const float*)d_in[7];
    const float* out_b0 = (const float*)d_in[8];
    const float* fc_w1 = (const float*)d_in[9];
    const float* al1 = (const float*)d_in[10];
    const float* ar1 = (const float*)d_in[11];
    const float* out_w1 = (const float*)d_in[12];
    const float* out_b1 = (const float*)d_in[13];
    const float* mlp_w = (const float*)d_in[14];
    const float* mlp_b = (const float*)d_in[15];
    float* out = (float*)d_out;

    char* p = (char*)d_ws;
    auto take = [&](size_t bytes) {
        char* cur = p;
        p += (bytes + 255) & ~(size_t)255;
        return cur;
    };
    __half* bp0 = (__half*)take(16384 * 2);
    __half* bp1 = (__half*)take(16384 * 2);
    __half* bpm = (__half*)take(32768 * 2);
    __half* feat_h = (__half*)take((size_t)BB * NN * 128 * 2);
    __half* hcat = (__half*)take((size_t)BB * NN * 256 * 2);
    float* el = (float*)take((size_t)BB * NN * HH * 4);
    float* er = (float*)take((size_t)BB * NN * HH * 4);
    int* cnt = (int*)take((size_t)NN * 4);
    int* cursor = (int*)take((size_t)NN * 4);
    int* row_off = (int*)take((size_t)(NN + 1) * 4);
    int* edge_ids = (int*)take((size_t)EE * 4);
    (void)ws_size; (void)in_sizes; (void)n_in; (void)out_size;

    // weight prep (+ counter zeroing) + CSR build
    pack_weights<<<128, 256, 0, stream>>>(fc_w0, fc_w1, mlp_w, bp0, bp1, bpm, cnt, cursor);
    count_edges<<<EE / 256, 256, 0, stream>>>(dst, cnt);
    scan_kernel<<<1, 1024, 0, stream>>>(cnt, row_off);
    scatter_edges<<<EE / 256, 256, 0, stream>>>(dst, row_off, cursor, edge_ids);

    const int GEMM_GRID = (BB * NN) / 64;  // 625
    const int ELR_GRID = (BB * NN * HH + 255) / 256;  // 625
    const int AGG_GRID = NN / 4;  // 2500

    // ---- layer 0 ----
    mfma_gemm<128, false, true, false><<<GEMM_GRID, 256, 0, stream>>>(
        features, 128, bp0, nullptr, feat_h, nullptr, 128);
    elr_kernel<<<ELR_GRID, 256, 0, stream>>>(feat_h, al0, ar0, el, er);
    gat_aggregate<<<AGG_GRID, 256, 0, stream>>>(row_off, edge_ids, src, edge_w, el, er,
                                                feat_h, out_w0, out_b0, hcat, 0);
    // ---- layer 1 ---- (input = hcat[:, 0:128] fp16, output -> hcat[:, 128:256])
    mfma_gemm<128, true, true, false><<<GEMM_GRID, 256, 0, stream>>>(
        hcat, 256, bp1, nullptr, feat_h, nullptr, 128);
    elr_kernel<<<ELR_GRID, 256, 0, stream>>>(feat_h, al1, ar1, el, er);
    gat_aggregate<<<AGG_GRID, 256, 0, stream>>>(row_off, edge_ids, src, edge_w, el, er,
                                                feat_h, out_w1, out_b1, hcat, 128);
    // ---- MLP head ---- (A = hcat fp16, K=256, fp32 out + bias)
    mfma_gemm<256, true, false, true><<<GEMM_GRID, 256, 0, stream>>>(
        hcat, 256, bpm, mlp_b, nullptr, out, 128);
}